// Round 12
// baseline (971.700 us; speedup 1.0000x reference)
//
#include <hip/hip_runtime.h>
#include <math.h>

#define NQ 14
#define NL 6
#define NT 512
#define NGATES (NL * NQ)
#define CHUNK 32            // amps per thread: amp = (tid<<5) | j
// amp bit p: p<5 local (register j bit p), 5<=p<11 lane bit (tid bit p-5),
//            p>=11 wave bit (tid bits 6..8). Wire w <-> amp bit P = 13-w.
// Spill control (R7..R11): allocator pins VGPR budget at 128 for NT=512 via
// every indirect knob (launch_bounds min-waves, waves_per_eu, static LDS all
// ignored). R12: direct directive amdgpu_num_vgpr(192) -> budget covers the
// ~160-reg scheduler peak; 192 VGPR + 32 KB LDS + no scratch still allows
// 2 blocks/CU (16 waves) -> double latency hiding.
// False-dependency guards (g = 0.f*ar[..]) bound the in-flight window in all
// multi-amp gate bodies; wave exchanges in 8-amp quarter phases.
// No sched_barrier (R8: pinned liveness, made spill worse).

using F4 = float4;

// ---- prep: Rot matrices (batch-shared) into d_ws ----
// Rot(phi,theta,omega) = RZ(omega) RY(theta) RZ(phi)
__global__ void prep_kernel(const float* __restrict__ wts, float* __restrict__ gm) {
    int g = blockIdx.x * blockDim.x + threadIdx.x;
    if (g < NGATES) {
        float phi = wts[g*3+0], th = wts[g*3+1], om = wts[g*3+2];
        float c = cosf(0.5f*th), s = sinf(0.5f*th);
        float a = 0.5f*(phi+om), bb = 0.5f*(phi-om);
        float ca = cosf(a), sa = sinf(a);
        float cb = cosf(bb), sb = sinf(bb);
        gm[g*8+0] = c*ca;  gm[g*8+1] = -c*sa;   // m00
        gm[g*8+2] = -s*cb; gm[g*8+3] = -s*sb;   // m01
        gm[g*8+4] = s*cb;  gm[g*8+5] = -s*sb;   // m10
        gm[g*8+6] = c*ca;  gm[g*8+7] = c*sa;    // m11
    }
}

// ---- Rot: lo' = m00*lo + m01*hi; hi' = m10*lo + m11*hi ----
template<int P>
__device__ __forceinline__ void rot_gate(float (&ar)[CHUNK], float (&ai)[CHUNK],
                                         const float* __restrict__ m, int tid, F4* buf) {
    if constexpr (P < 5) {
        constexpr int M = 1 << P;
        float m0=m[0],m1=m[1],m2=m[2],m3=m[3],m4=m[4],m5=m[5],m6=m[6],m7=m[7];
        float g = 0.f;   // false-dep guard: bounds in-flight pairs to 4
        #pragma unroll
        for (int B = 0; B < CHUNK/2; B += 4) {
            #pragma unroll
            for (int i = B; i < B+4; ++i) {
                int j0 = ((i >> P) << (P+1)) | (i & (M-1));
                int j1 = j0 | M;
                float r0=ar[j0]+g, i0=ai[j0]+g, r1=ar[j1], i1=ai[j1];
                ar[j0] = m0*r0 - m1*i0 + m2*r1 - m3*i1;
                ai[j0] = m0*i0 + m1*r0 + m2*i1 + m3*r1;
                ar[j1] = m4*r0 - m5*i0 + m6*r1 - m7*i1;
                ai[j1] = m4*i0 + m5*r0 + m6*i1 + m7*r1;
            }
            {
                int last = ((B+3) >> P << (P+1)) | ((B+3) & (M-1));
                g = 0.f * ar[last];
            }
        }
    } else if constexpr (P < 11) {
        constexpr int LM = 1 << (P-5);
        int bit = (tid >> (P-5)) & 1;
        float cAr = bit ? m[6] : m[0];
        float cAi = bit ? m[7] : m[1];
        float cBr = bit ? m[4] : m[2];
        float cBi = bit ? m[5] : m[3];
        float g = 0.f;   // false-dep guard: serializes 8-amp chunks
        #pragma unroll
        for (int B = 0; B < CHUNK; B += 8) {
            #pragma unroll
            for (int j = B; j < B+8; ++j) {
                float aj = ar[j] + g;
                float bj = ai[j] + g;
                float br = __shfl_xor(aj, LM, 64);
                float bi = __shfl_xor(bj, LM, 64);
                float nr = cAr*aj - cAi*bj + cBr*br - cBi*bi;
                float ni = cAr*bj + cAi*aj + cBr*bi + cBi*br;
                ar[j] = nr; ai[j] = ni;
            }
            g = 0.f * ar[B + 7];
        }
    } else {
        constexpr int WM = 1 << (P-5);
        int ptid = tid ^ WM;
        int bit = (tid >> (P-5)) & 1;
        float cAr = bit ? m[6] : m[0];
        float cAi = bit ? m[7] : m[1];
        float cBr = bit ? m[4] : m[2];
        float cBi = bit ? m[5] : m[3];
        // quarter phases: 8 amps (2 F4 re + 2 F4 im) per phase
        #pragma unroll
        for (int h = 0; h < 4; ++h) {
            int j = 8*h;
            buf[0*NT + tid] = make_float4(ar[j],  ar[j+1],ar[j+2],ar[j+3]);
            buf[1*NT + tid] = make_float4(ar[j+4],ar[j+5],ar[j+6],ar[j+7]);
            buf[2*NT + tid] = make_float4(ai[j],  ai[j+1],ai[j+2],ai[j+3]);
            buf[3*NT + tid] = make_float4(ai[j+4],ai[j+5],ai[j+6],ai[j+7]);
            __syncthreads();
            F4 pr0 = buf[0*NT + ptid], pr1 = buf[1*NT + ptid];
            F4 pi0 = buf[2*NT + ptid], pi1 = buf[3*NT + ptid];
            float prx[8] = {pr0.x,pr0.y,pr0.z,pr0.w, pr1.x,pr1.y,pr1.z,pr1.w};
            float pix[8] = {pi0.x,pi0.y,pi0.z,pi0.w, pi1.x,pi1.y,pi1.z,pi1.w};
            #pragma unroll
            for (int q = 0; q < 8; ++q) {
                float nr = cAr*ar[j+q] - cAi*ai[j+q] + cBr*prx[q] - cBi*pix[q];
                float ni = cAr*ai[j+q] + cAi*ar[j+q] + cBr*pix[q] + cBi*prx[q];
                ar[j+q] = nr; ai[j+q] = ni;
            }
            __syncthreads();
        }
    }
}

// ---- CNOT(ctrl bit PC, target bit PT) ----
template<int PC, int PT>
__device__ __forceinline__ void cnot_gate(float (&ar)[CHUNK], float (&ai)[CHUNK],
                                          int tid, F4* buf) {
    if constexpr (PT < 5) {
        constexpr int TM = 1 << PT;
        if constexpr (PC < 5) {
            constexpr int CM = 1 << PC;
            // pure register permutation; compiler renames, no pressure
            #pragma unroll
            for (int j = 0; j < CHUNK; ++j) {
                if ((j & CM) && !(j & TM)) {
                    int j1 = j | TM;
                    float t = ar[j]; ar[j] = ar[j1]; ar[j1] = t;
                    t = ai[j]; ai[j] = ai[j1]; ai[j1] = t;
                }
            }
        } else {
            int sel = (tid >> (PC-5)) & 1;
            float g = 0.f;   // guard: 4 pairs in flight
            #pragma unroll
            for (int B = 0; B < CHUNK/2; B += 4) {
                #pragma unroll
                for (int i = B; i < B+4; ++i) {
                    int j0 = ((i >> PT) << (PT+1)) | (i & (TM-1));
                    int j1 = j0 | TM;
                    float a = ar[j0]+g, bv = ar[j1];
                    ar[j0] = sel ? bv : a; ar[j1] = sel ? a : bv;
                    a = ai[j0]; bv = ai[j1];
                    ai[j0] = sel ? bv : a; ai[j1] = sel ? a : bv;
                }
                {
                    int last = ((B+3) >> PT << (PT+1)) | ((B+3) & (TM-1));
                    g = 0.f * ar[last];
                }
            }
        }
    } else if constexpr (PT < 11) {
        constexpr int LM = 1 << (PT-5);
        if constexpr (PC < 5) {
            constexpr int CM = 1 << PC;
            float g = 0.f;
            #pragma unroll
            for (int B = 0; B < CHUNK; B += 8) {
                #pragma unroll
                for (int j = B; j < B+8; ++j) {
                    if (j & CM) {
                        ar[j] = __shfl_xor(ar[j] + g, LM, 64);
                        ai[j] = __shfl_xor(ai[j] + g, LM, 64);
                    }
                }
                if ((B + 7) & CM) g = 0.f * ar[B + 7];
            }
        } else {
            int sel = (tid >> (PC-5)) & 1;
            if (sel) {  // partner differs only in PT lane bit -> same sel
                float g = 0.f;
                #pragma unroll
                for (int B = 0; B < CHUNK; B += 8) {
                    #pragma unroll
                    for (int j = B; j < B+8; ++j) {
                        ar[j] = __shfl_xor(ar[j] + g, LM, 64);
                        ai[j] = __shfl_xor(ai[j] + g, LM, 64);
                    }
                    g = 0.f * ar[B + 7];
                }
            }
        }
    } else {
        constexpr int WM = 1 << (PT-5);
        int ptid = tid ^ WM;
        if constexpr (PC < 5) {
            constexpr int CM = 1 << PC;
            // exchange the 16 ctrl==1 amps in 2 phases of 8
            #pragma unroll
            for (int h = 0; h < 2; ++h) {
                float v[16];
                #pragma unroll
                for (int q = 0; q < 8; ++q) {
                    int i = 8*h + q;
                    int j = ((i >> PC) << (PC+1)) | (i & (CM-1)) | CM;
                    v[q] = ar[j]; v[8+q] = ai[j];
                }
                buf[0*NT + tid] = make_float4(v[0], v[1], v[2], v[3]);
                buf[1*NT + tid] = make_float4(v[4], v[5], v[6], v[7]);
                buf[2*NT + tid] = make_float4(v[8], v[9], v[10],v[11]);
                buf[3*NT + tid] = make_float4(v[12],v[13],v[14],v[15]);
                __syncthreads();
                F4 pr0 = buf[0*NT + ptid], pr1 = buf[1*NT + ptid];
                F4 pi0 = buf[2*NT + ptid], pi1 = buf[3*NT + ptid];
                float prx[8] = {pr0.x,pr0.y,pr0.z,pr0.w, pr1.x,pr1.y,pr1.z,pr1.w};
                float pix[8] = {pi0.x,pi0.y,pi0.z,pi0.w, pi1.x,pi1.y,pi1.z,pi1.w};
                #pragma unroll
                for (int q = 0; q < 8; ++q) {
                    int i = 8*h + q;
                    int j = ((i >> PC) << (PC+1)) | (i & (CM-1)) | CM;
                    ar[j] = prx[q]; ai[j] = pix[q];
                }
                __syncthreads();
            }
        } else {
            // ctrl is a thread bit != PT: sel==1 threads swap whole chunk,
            // in 4 quarter phases
            int sel = (tid >> (PC-5)) & 1;
            #pragma unroll
            for (int h = 0; h < 4; ++h) {
                int j = 8*h;
                if (sel) {
                    buf[0*NT + tid] = make_float4(ar[j],  ar[j+1],ar[j+2],ar[j+3]);
                    buf[1*NT + tid] = make_float4(ar[j+4],ar[j+5],ar[j+6],ar[j+7]);
                    buf[2*NT + tid] = make_float4(ai[j],  ai[j+1],ai[j+2],ai[j+3]);
                    buf[3*NT + tid] = make_float4(ai[j+4],ai[j+5],ai[j+6],ai[j+7]);
                }
                __syncthreads();
                if (sel) {
                    F4 pr0 = buf[0*NT + ptid], pr1 = buf[1*NT + ptid];
                    F4 pi0 = buf[2*NT + ptid], pi1 = buf[3*NT + ptid];
                    ar[j]  =pr0.x; ar[j+1]=pr0.y; ar[j+2]=pr0.z; ar[j+3]=pr0.w;
                    ar[j+4]=pr1.x; ar[j+5]=pr1.y; ar[j+6]=pr1.z; ar[j+7]=pr1.w;
                    ai[j]  =pi0.x; ai[j+1]=pi0.y; ai[j+2]=pi0.z; ai[j+3]=pi0.w;
                    ai[j+4]=pi1.x; ai[j+5]=pi1.y; ai[j+6]=pi1.z; ai[j+7]=pi1.w;
                }
                __syncthreads();
            }
        }
    }
}

// ---- compile-time circuit drivers ----
template<int L, int W>
__device__ __forceinline__ void do_rots(float (&ar)[CHUNK], float (&ai)[CHUNK],
                                        const float* __restrict__ gm, int tid, F4* buf) {
    rot_gate<13-W>(ar, ai, gm + (L*NQ + W)*8, tid, buf);
    if constexpr (W < NQ-1) do_rots<L, W+1>(ar, ai, gm, tid, buf);
}

template<int L, int W>
__device__ __forceinline__ void do_cnots(float (&ar)[CHUNK], float (&ai)[CHUNK],
                                         int tid, F4* buf) {
    constexpr int R = (L % (NQ-1)) + 1;
    constexpr int TW = (W + R) % NQ;
    cnot_gate<13-W, 13-TW>(ar, ai, tid, buf);
    if constexpr (W < NQ-1) do_cnots<L, W+1>(ar, ai, tid, buf);
}

template<int L>
__device__ __forceinline__ void do_layer(float (&ar)[CHUNK], float (&ai)[CHUNK],
                                         const float* __restrict__ gm, int tid, F4* buf) {
    do_rots<L, 0>(ar, ai, gm, tid, buf);
    do_cnots<L, 0>(ar, ai, tid, buf);
    if constexpr (L < NL-1) do_layer<L+1>(ar, ai, gm, tid, buf);
}

__global__ void __launch_bounds__(NT)
__attribute__((amdgpu_num_vgpr(192)))   // direct allocator directive: budget 192
qsim_kernel(
    const float* __restrict__ x,
    const float* __restrict__ gm,
    float* __restrict__ out)
{
    __shared__ F4 buf[4 * NT];   // static 32 KB; 2 blocks/CU at 192 VGPRs
    const int tid = threadIdx.x;
    const int b = blockIdx.x;
    const float* xb = x + b * NQ;

    // ---- direct product-state init: state after RX(x_w) on |0..0> ----
    // amp(p) = prod_bits [ bit ? -i*sin(x/2) : cos(x/2) ]
    float ar[CHUNK], ai[CHUNK];
    {
        // thread-common factor over tid bits 0..8 (amp bit 5+bb, wire 8-bb)
        float cr = 1.f, ci = 0.f;
        #pragma unroll
        for (int bb = 0; bb < 9; ++bb) {
            float t = xb[8 - bb];
            float c = cosf(0.5f*t), s = sinf(0.5f*t);
            if ((tid >> bb) & 1) { float nr = s*ci, ni = -s*cr; cr = nr; ci = ni; }
            else                 { cr *= c; ci *= c; }
        }
        // local bits 0..4 (amp bit bb, wire 13-bb)
        float lc[5], ls[5];
        #pragma unroll
        for (int bb = 0; bb < 5; ++bb) {
            float t = xb[13 - bb];
            lc[bb] = cosf(0.5f*t); ls[bb] = sinf(0.5f*t);
        }
        float g = 0.f;
        #pragma unroll
        for (int B = 0; B < CHUNK; B += 8) {
            #pragma unroll
            for (int j = B; j < B+8; ++j) {
                float rr = cr + g, ii = ci;
                #pragma unroll
                for (int bb = 0; bb < 5; ++bb) {
                    if ((j >> bb) & 1) { float nr = ls[bb]*ii, ni = -ls[bb]*rr; rr = nr; ii = ni; }
                    else               { rr *= lc[bb]; ii *= lc[bb]; }
                }
                ar[j] = rr; ai[j] = ii;
            }
            g = 0.f * ar[B + 7];
        }
    }
    __syncthreads();

    do_layer<0>(ar, ai, gm, tid, buf);

    // <Z0>: amp bit 13 = tid bit 8 -> sign uniform per thread
    float acc = 0.f;
    #pragma unroll
    for (int j = 0; j < CHUNK; ++j) acc += ar[j]*ar[j] + ai[j]*ai[j];
    if (tid & 256) acc = -acc;
    #pragma unroll
    for (int off = 32; off > 0; off >>= 1) acc += __shfl_down(acc, off, 64);
    __syncthreads();
    float* f = (float*)buf;
    if ((tid & 63) == 0) f[tid >> 6] = acc;
    __syncthreads();
    if (tid == 0) {
        float s = 0.f;
        #pragma unroll
        for (int w = 0; w < NT/64; ++w) s += f[w];
        out[b] = s;
    }
}

extern "C" void kernel_launch(void* const* d_in, const int* in_sizes, int n_in,
                              void* d_out, int out_size, void* d_ws, size_t ws_size,
                              hipStream_t stream) {
    const float* x = (const float*)d_in[0];   // (1024, 14) float32
    const float* w = (const float*)d_in[1];   // (6, 14, 3) float32
    float* out = (float*)d_out;               // (1024,) float32
    float* gm = (float*)d_ws;                 // 84*8 floats of Rot matrices

    prep_kernel<<<1, 128, 0, stream>>>(w, gm);
    qsim_kernel<<<out_size, NT, 0, stream>>>(x, gm, out);
}

// Round 13
// 524.345 us; speedup vs baseline: 1.8532x; 1.8532x over previous
//
#include <hip/hip_runtime.h>
#include <hip/hip_fp16.h>
#include <math.h>

#define NQ 14
#define NL 6
#define NT 1024
#define NGATES (NL * NQ)
#define NK 8   // 8 half2 regs per re/im array = 16 amps/thread
// amp index p = (tid<<4) | j, j=0..15. Packing: bit 3 of j -> half2 halves:
// pk[k] = (amp j=k [lo], amp j=k|8 [hi]), k=0..7.
// amp bit p: p<3 local k-bit (packed gates), p==3 packing bit (cross-half),
// 4<=p<10 lane bit (tid bit p-4, shuffles), p>=10 wave bit (tid bits 6..9,
// LDS exchange). Wire w <-> amp bit P = 13-w.
// fp16 state = 16 VGPRs -> demand ~50 fits the 64-VGPR budget the backend
// pins on NT=1024 kernels (R1..R12: every budget-raise knob ignored) ->
// spill-free by construction; packed math halves VALU+DS work; 32 KB LDS
// -> 2 blocks/CU (100% occupancy).

using F4 = float4;
using H2 = __half2;

__device__ __forceinline__ unsigned h2u(H2 v){ return __builtin_bit_cast(unsigned, v); }
__device__ __forceinline__ H2 u2h(unsigned x){ return __builtin_bit_cast(H2, x); }
__device__ __forceinline__ float h2f(H2 v){ return __builtin_bit_cast(float, v); }
__device__ __forceinline__ H2 f2h(float x){ return __builtin_bit_cast(H2, x); }
__device__ __forceinline__ H2 bc(float x){ return __float2half2_rn(x); }
__device__ __forceinline__ H2 shflx(H2 v, int m){
    return u2h((unsigned)__shfl_xor((int)h2u(v), m, 64));
}

// ---- prep: Rot matrices (batch-shared, fp32) into d_ws ----
__global__ void prep_kernel(const float* __restrict__ wts, float* __restrict__ gm) {
    int g = blockIdx.x * blockDim.x + threadIdx.x;
    if (g < NGATES) {
        float phi = wts[g*3+0], th = wts[g*3+1], om = wts[g*3+2];
        float c = cosf(0.5f*th), s = sinf(0.5f*th);
        float a = 0.5f*(phi+om), bb = 0.5f*(phi-om);
        float ca = cosf(a), sa = sinf(a);
        float cb = cosf(bb), sb = sinf(bb);
        gm[g*8+0] = c*ca;  gm[g*8+1] = -c*sa;   // m00
        gm[g*8+2] = -s*cb; gm[g*8+3] = -s*sb;   // m01
        gm[g*8+4] = s*cb;  gm[g*8+5] = -s*sb;   // m10
        gm[g*8+6] = c*ca;  gm[g*8+7] = c*sa;    // m11
    }
}

// ---- Rot on amp bit P ----
template<int P>
__device__ __forceinline__ void rot_gate(H2 (&pr)[NK], H2 (&pi)[NK],
                                         const float* __restrict__ m, int tid, F4* buf) {
    float m0=m[0],m1=m[1],m2=m[2],m3=m[3],m4=m[4],m5=m[5],m6=m[6],m7=m[7];
    if constexpr (P < 3) {
        constexpr int M = 1 << P;
        H2 h0=bc(m0),h1=bc(m1),nh1=bc(-m1),h2v=bc(m2),h3=bc(m3),nh3=bc(-m3);
        H2 h4=bc(m4),h5=bc(m5),nh5=bc(-m5),h6=bc(m6),h7=bc(m7),nh7=bc(-m7);
        #pragma unroll
        for (int i = 0; i < 4; ++i) {
            int k0 = ((i >> P) << (P+1)) | (i & (M-1));
            int k1 = k0 | M;
            H2 r0=pr[k0], i0=pi[k0], r1=pr[k1], i1=pi[k1];
            pr[k0] = __hfma2(h0,r0,__hfma2(nh1,i0,__hfma2(h2v,r1,__hmul2(nh3,i1))));
            pi[k0] = __hfma2(h0,i0,__hfma2(h1,r0,__hfma2(h2v,i1,__hmul2(h3,r1))));
            pr[k1] = __hfma2(h4,r0,__hfma2(nh5,i0,__hfma2(h6,r1,__hmul2(nh7,i1))));
            pi[k1] = __hfma2(h4,i0,__hfma2(h5,r0,__hfma2(h6,i1,__hmul2(h7,r1))));
        }
    } else if constexpr (P == 3) {
        // cross-half: pairs are (lo, hi) of each reg; fp32 math
        #pragma unroll
        for (int k = 0; k < NK; ++k) {
            float r0=__low2float(pr[k]), r1=__high2float(pr[k]);
            float i0=__low2float(pi[k]), i1=__high2float(pi[k]);
            float lr = m0*r0 - m1*i0 + m2*r1 - m3*i1;
            float li = m0*i0 + m1*r0 + m2*i1 + m3*r1;
            float hr = m4*r0 - m5*i0 + m6*r1 - m7*i1;
            float hi = m4*i0 + m5*r0 + m6*i1 + m7*r1;
            pr[k] = __floats2half2_rn(lr, hr);
            pi[k] = __floats2half2_rn(li, hi);
        }
    } else if constexpr (P < 10) {
        constexpr int LM = 1 << (P-4);
        int bit = (tid >> (P-4)) & 1;
        float cAr = bit ? m6 : m0, cAi = bit ? m7 : m1;
        float cBr = bit ? m4 : m2, cBi = bit ? m5 : m3;
        H2 a=bc(cAr), ai2=bc(cAi), nai=bc(-cAi), b2=bc(cBr), bi2=bc(cBi), nbi=bc(-cBi);
        #pragma unroll
        for (int k = 0; k < NK; ++k) {
            H2 r = pr[k], i = pi[k];
            H2 qr = shflx(r, LM), qi = shflx(i, LM);
            pr[k] = __hfma2(a,r,__hfma2(nai,i,__hfma2(b2,qr,__hmul2(nbi,qi))));
            pi[k] = __hfma2(a,i,__hfma2(ai2,r,__hfma2(b2,qi,__hmul2(bi2,qr))));
        }
    } else {
        constexpr int WM = 1 << (P-4);
        int ptid = tid ^ WM;
        int bit = (tid >> (P-4)) & 1;
        float cAr = bit ? m6 : m0, cAi = bit ? m7 : m1;
        float cBr = bit ? m4 : m2, cBi = bit ? m5 : m3;
        H2 a=bc(cAr), ai2=bc(cAi), nai=bc(-cAi), b2=bc(cBr), bi2=bc(cBi), nbi=bc(-cBi);
        H2 qr[NK], qi[NK];
        buf[tid]    = make_float4(h2f(pr[0]),h2f(pr[1]),h2f(pr[2]),h2f(pr[3]));
        buf[NT+tid] = make_float4(h2f(pr[4]),h2f(pr[5]),h2f(pr[6]),h2f(pr[7]));
        __syncthreads();
        { F4 x = buf[ptid], y = buf[NT+ptid];
          qr[0]=f2h(x.x); qr[1]=f2h(x.y); qr[2]=f2h(x.z); qr[3]=f2h(x.w);
          qr[4]=f2h(y.x); qr[5]=f2h(y.y); qr[6]=f2h(y.z); qr[7]=f2h(y.w); }
        __syncthreads();
        buf[tid]    = make_float4(h2f(pi[0]),h2f(pi[1]),h2f(pi[2]),h2f(pi[3]));
        buf[NT+tid] = make_float4(h2f(pi[4]),h2f(pi[5]),h2f(pi[6]),h2f(pi[7]));
        __syncthreads();
        { F4 x = buf[ptid], y = buf[NT+ptid];
          qi[0]=f2h(x.x); qi[1]=f2h(x.y); qi[2]=f2h(x.z); qi[3]=f2h(x.w);
          qi[4]=f2h(y.x); qi[5]=f2h(y.y); qi[6]=f2h(y.z); qi[7]=f2h(y.w); }
        __syncthreads();
        #pragma unroll
        for (int k = 0; k < NK; ++k) {
            H2 r = pr[k], i = pi[k];
            pr[k] = __hfma2(a,r,__hfma2(nai,i,__hfma2(b2,qr[k],__hmul2(nbi,qi[k]))));
            pi[k] = __hfma2(a,i,__hfma2(ai2,r,__hfma2(b2,qi[k],__hmul2(bi2,qr[k]))));
        }
    }
}

// ---- CNOT(ctrl bit PC, target bit PT) ----
template<int PC, int PT>
__device__ __forceinline__ void cnot_gate(H2 (&pr)[NK], H2 (&pi)[NK], int tid, F4* buf) {
    if constexpr (PT < 3) {
        constexpr int TM = 1 << PT;
        if constexpr (PC < 3) {
            constexpr int CM = 1 << PC;
            #pragma unroll
            for (int k = 0; k < NK; ++k)
                if ((k & CM) && !(k & TM)) {
                    int k1 = k | TM;
                    H2 t = pr[k]; pr[k] = pr[k1]; pr[k1] = t;
                    t = pi[k]; pi[k] = pi[k1]; pi[k1] = t;
                }
        } else if constexpr (PC == 3) {
            // ctrl = packing bit: swap only high halves of (k, k|TM)
            #pragma unroll
            for (int k = 0; k < NK; ++k)
                if (!(k & TM)) {
                    int k1 = k | TM;
                    unsigned A = h2u(pr[k]), B = h2u(pr[k1]);
                    pr[k]  = u2h((A & 0xFFFFu) | (B & 0xFFFF0000u));
                    pr[k1] = u2h((B & 0xFFFFu) | (A & 0xFFFF0000u));
                    A = h2u(pi[k]); B = h2u(pi[k1]);
                    pi[k]  = u2h((A & 0xFFFFu) | (B & 0xFFFF0000u));
                    pi[k1] = u2h((B & 0xFFFFu) | (A & 0xFFFF0000u));
                }
        } else if constexpr (PC < 10) {
            int sel = (tid >> (PC-4)) & 1;
            #pragma unroll
            for (int k = 0; k < NK; ++k)
                if (!(k & TM)) {
                    int k1 = k | TM;
                    H2 A = pr[k], B = pr[k1];
                    pr[k] = sel ? B : A; pr[k1] = sel ? A : B;
                    A = pi[k]; B = pi[k1];
                    pi[k] = sel ? B : A; pi[k1] = sel ? A : B;
                }
        } else {
            int sel = (tid >> (PC-4)) & 1;
            if (sel) {
                #pragma unroll
                for (int k = 0; k < NK; ++k)
                    if (!(k & TM)) {
                        int k1 = k | TM;
                        H2 t = pr[k]; pr[k] = pr[k1]; pr[k1] = t;
                        t = pi[k]; pi[k] = pi[k1]; pi[k1] = t;
                    }
            }
        }
    } else if constexpr (PT == 3) {
        // target = packing bit: swap halves where ctrl==1
        if constexpr (PC < 3) {
            constexpr int CM = 1 << PC;
            #pragma unroll
            for (int k = 0; k < NK; ++k)
                if (k & CM) {
                    unsigned A = h2u(pr[k]); pr[k] = u2h((A>>16)|(A<<16));
                    A = h2u(pi[k]); pi[k] = u2h((A>>16)|(A<<16));
                }
        } else if constexpr (PC < 10) {
            int sel = (tid >> (PC-4)) & 1;
            #pragma unroll
            for (int k = 0; k < NK; ++k) {
                unsigned A = h2u(pr[k]), S = (A>>16)|(A<<16);
                pr[k] = u2h(sel ? S : A);
                A = h2u(pi[k]); S = (A>>16)|(A<<16);
                pi[k] = u2h(sel ? S : A);
            }
        } else {
            int sel = (tid >> (PC-4)) & 1;
            if (sel) {
                #pragma unroll
                for (int k = 0; k < NK; ++k) {
                    unsigned A = h2u(pr[k]); pr[k] = u2h((A>>16)|(A<<16));
                    A = h2u(pi[k]); pi[k] = u2h((A>>16)|(A<<16));
                }
            }
        }
    } else if constexpr (PT < 10) {
        constexpr int LM = 1 << (PT-4);
        if constexpr (PC < 3) {
            constexpr int CM = 1 << PC;
            #pragma unroll
            for (int k = 0; k < NK; ++k)
                if (k & CM) { pr[k] = shflx(pr[k], LM); pi[k] = shflx(pi[k], LM); }
        } else if constexpr (PC == 3) {
            // only high halves exchange between partner lanes
            #pragma unroll
            for (int k = 0; k < NK; ++k) {
                unsigned S = h2u(shflx(pr[k], LM));
                pr[k] = u2h((h2u(pr[k]) & 0xFFFFu) | (S & 0xFFFF0000u));
                S = h2u(shflx(pi[k], LM));
                pi[k] = u2h((h2u(pi[k]) & 0xFFFFu) | (S & 0xFFFF0000u));
            }
        } else if constexpr (PC < 10) {
            int sel = (tid >> (PC-4)) & 1;   // partner (xor PT lane bit) has same sel
            #pragma unroll
            for (int k = 0; k < NK; ++k) {
                H2 sr = shflx(pr[k], LM), si = shflx(pi[k], LM);
                pr[k] = sel ? sr : pr[k];
                pi[k] = sel ? si : pi[k];
            }
        } else {
            int sel = (tid >> (PC-4)) & 1;
            if (sel) {
                #pragma unroll
                for (int k = 0; k < NK; ++k) { pr[k]=shflx(pr[k],LM); pi[k]=shflx(pi[k],LM); }
            }
        }
    } else {
        constexpr int WM = 1 << (PT-4);
        int ptid = tid ^ WM;
        if constexpr (PC < 3) {
            constexpr int CM = 1 << PC;
            // exactly 4 of 8 regs selected (both halves: ctrl is a k-bit)
            H2 vr[4], vi[4];
            { int c = 0;
              #pragma unroll
              for (int k = 0; k < NK; ++k)
                  if (k & CM) { vr[c]=pr[k]; vi[c]=pi[k]; ++c; } }
            buf[tid]    = make_float4(h2f(vr[0]),h2f(vr[1]),h2f(vr[2]),h2f(vr[3]));
            buf[NT+tid] = make_float4(h2f(vi[0]),h2f(vi[1]),h2f(vi[2]),h2f(vi[3]));
            __syncthreads();
            F4 x = buf[ptid], y = buf[NT+ptid];
            __syncthreads();
            H2 wr[4] = {f2h(x.x),f2h(x.y),f2h(x.z),f2h(x.w)};
            H2 wi[4] = {f2h(y.x),f2h(y.y),f2h(y.z),f2h(y.w)};
            { int c = 0;
              #pragma unroll
              for (int k = 0; k < NK; ++k)
                  if (k & CM) { pr[k]=wr[c]; pi[k]=wi[c]; ++c; } }
        } else if constexpr (PC == 3) {
            // only high halves exchange with partner thread
            unsigned er[4], ei[4];
            #pragma unroll
            for (int t = 0; t < 4; ++t) {
                er[t] = (h2u(pr[2*t]) >> 16) | (h2u(pr[2*t+1]) & 0xFFFF0000u);
                ei[t] = (h2u(pi[2*t]) >> 16) | (h2u(pi[2*t+1]) & 0xFFFF0000u);
            }
            buf[tid]    = make_float4(__builtin_bit_cast(float,er[0]),__builtin_bit_cast(float,er[1]),
                                      __builtin_bit_cast(float,er[2]),__builtin_bit_cast(float,er[3]));
            buf[NT+tid] = make_float4(__builtin_bit_cast(float,ei[0]),__builtin_bit_cast(float,ei[1]),
                                      __builtin_bit_cast(float,ei[2]),__builtin_bit_cast(float,ei[3]));
            __syncthreads();
            F4 x = buf[ptid], y = buf[NT+ptid];
            __syncthreads();
            unsigned fr[4] = {__builtin_bit_cast(unsigned,x.x),__builtin_bit_cast(unsigned,x.y),
                              __builtin_bit_cast(unsigned,x.z),__builtin_bit_cast(unsigned,x.w)};
            unsigned fi[4] = {__builtin_bit_cast(unsigned,y.x),__builtin_bit_cast(unsigned,y.y),
                              __builtin_bit_cast(unsigned,y.z),__builtin_bit_cast(unsigned,y.w)};
            #pragma unroll
            for (int t = 0; t < 4; ++t) {
                pr[2*t]   = u2h((h2u(pr[2*t])   & 0xFFFFu) | (fr[t] << 16));
                pr[2*t+1] = u2h((h2u(pr[2*t+1]) & 0xFFFFu) | (fr[t] & 0xFFFF0000u));
                pi[2*t]   = u2h((h2u(pi[2*t])   & 0xFFFFu) | (fi[t] << 16));
                pi[2*t+1] = u2h((h2u(pi[2*t+1]) & 0xFFFFu) | (fi[t] & 0xFFFF0000u));
            }
        } else {
            // ctrl is a thread bit != PT: sel==1 threads swap whole state
            int sel = (tid >> (PC-4)) & 1;
            if (sel) {
                buf[tid]    = make_float4(h2f(pr[0]),h2f(pr[1]),h2f(pr[2]),h2f(pr[3]));
                buf[NT+tid] = make_float4(h2f(pr[4]),h2f(pr[5]),h2f(pr[6]),h2f(pr[7]));
            }
            __syncthreads();
            if (sel) {
                F4 x = buf[ptid], y = buf[NT+ptid];
                pr[0]=f2h(x.x); pr[1]=f2h(x.y); pr[2]=f2h(x.z); pr[3]=f2h(x.w);
                pr[4]=f2h(y.x); pr[5]=f2h(y.y); pr[6]=f2h(y.z); pr[7]=f2h(y.w);
            }
            __syncthreads();
            if (sel) {
                buf[tid]    = make_float4(h2f(pi[0]),h2f(pi[1]),h2f(pi[2]),h2f(pi[3]));
                buf[NT+tid] = make_float4(h2f(pi[4]),h2f(pi[5]),h2f(pi[6]),h2f(pi[7]));
            }
            __syncthreads();
            if (sel) {
                F4 x = buf[ptid], y = buf[NT+ptid];
                pi[0]=f2h(x.x); pi[1]=f2h(x.y); pi[2]=f2h(x.z); pi[3]=f2h(x.w);
                pi[4]=f2h(y.x); pi[5]=f2h(y.y); pi[6]=f2h(y.z); pi[7]=f2h(y.w);
            }
            __syncthreads();
        }
    }
}

// ---- compile-time circuit drivers ----
template<int L, int W>
__device__ __forceinline__ void do_rots(H2 (&pr)[NK], H2 (&pi)[NK],
                                        const float* __restrict__ gm, int tid, F4* buf) {
    rot_gate<13-W>(pr, pi, gm + (L*NQ + W)*8, tid, buf);
    if constexpr (W < NQ-1) do_rots<L, W+1>(pr, pi, gm, tid, buf);
}

template<int L, int W>
__device__ __forceinline__ void do_cnots(H2 (&pr)[NK], H2 (&pi)[NK], int tid, F4* buf) {
    constexpr int R = (L % (NQ-1)) + 1;
    constexpr int TW = (W + R) % NQ;
    cnot_gate<13-W, 13-TW>(pr, pi, tid, buf);
    if constexpr (W < NQ-1) do_cnots<L, W+1>(pr, pi, tid, buf);
}

template<int L>
__device__ __forceinline__ void do_layer(H2 (&pr)[NK], H2 (&pi)[NK],
                                         const float* __restrict__ gm, int tid, F4* buf) {
    do_rots<L, 0>(pr, pi, gm, tid, buf);
    do_cnots<L, 0>(pr, pi, tid, buf);
    if constexpr (L < NL-1) do_layer<L+1>(pr, pi, gm, tid, buf);
}

__global__ void __launch_bounds__(NT)
qsim_kernel(
    const float* __restrict__ x,
    const float* __restrict__ gm,
    float* __restrict__ out)
{
    __shared__ F4 buf[2 * NT];   // static 32 KB exchange buffer -> 2 blocks/CU
    const int tid = threadIdx.x;
    const int b = blockIdx.x;
    const float* xb = x + b * NQ;

    // ---- direct product-state init (fp32 math, pack to fp16) ----
    // amp(p) = prod_bits [ bit ? -i*sin(x/2) : cos(x/2) ]
    H2 pr[NK], pi[NK];
    {
        float cr = 1.f, ci = 0.f;
        #pragma unroll
        for (int bb = 0; bb < 10; ++bb) {      // tid bit bb = amp bit 4+bb = wire 9-bb
            float t = xb[9 - bb];
            float c = cosf(0.5f*t), s = sinf(0.5f*t);
            if ((tid >> bb) & 1) { float nr = s*ci, ni = -s*cr; cr = nr; ci = ni; }
            else                 { cr *= c; ci *= c; }
        }
        float lc[4], ls[4];                     // j bit bb = wire 13-bb
        #pragma unroll
        for (int bb = 0; bb < 4; ++bb) {
            float t = xb[13 - bb];
            lc[bb] = cosf(0.5f*t); ls[bb] = sinf(0.5f*t);
        }
        #pragma unroll
        for (int k = 0; k < NK; ++k) {
            float rr = cr, ii = ci;
            #pragma unroll
            for (int bb = 0; bb < 3; ++bb) {
                if ((k >> bb) & 1) { float nr = ls[bb]*ii, ni = -ls[bb]*rr; rr = nr; ii = ni; }
                else               { rr *= lc[bb]; ii *= lc[bb]; }
            }
            // packing bit 3: lo = *cos, hi = -i*sin rotation
            pr[k] = __floats2half2_rn(rr*lc[3],  ls[3]*ii);
            pi[k] = __floats2half2_rn(ii*lc[3], -ls[3]*rr);
        }
    }
    __syncthreads();

    do_layer<0>(pr, pi, gm, tid, buf);

    // <Z0>: amp bit 13 = tid bit 9 -> sign uniform per thread
    float acc = 0.f;
    #pragma unroll
    for (int k = 0; k < NK; ++k) {
        float a=__low2float(pr[k]), bb=__high2float(pr[k]);
        float c=__low2float(pi[k]), d=__high2float(pi[k]);
        acc += a*a + bb*bb + c*c + d*d;
    }
    if (tid & 512) acc = -acc;
    #pragma unroll
    for (int off = 32; off > 0; off >>= 1) acc += __shfl_down(acc, off, 64);
    __syncthreads();
    float* f = (float*)buf;
    if ((tid & 63) == 0) f[tid >> 6] = acc;
    __syncthreads();
    if (tid == 0) {
        float s = 0.f;
        #pragma unroll
        for (int w = 0; w < NT/64; ++w) s += f[w];
        out[b] = s;
    }
}

extern "C" void kernel_launch(void* const* d_in, const int* in_sizes, int n_in,
                              void* d_out, int out_size, void* d_ws, size_t ws_size,
                              hipStream_t stream) {
    const float* x = (const float*)d_in[0];   // (1024, 14) float32
    const float* w = (const float*)d_in[1];   // (6, 14, 3) float32
    float* out = (float*)d_out;               // (1024,) float32
    float* gm = (float*)d_ws;                 // 84*8 floats of Rot matrices

    prep_kernel<<<1, 128, 0, stream>>>(w, gm);
    qsim_kernel<<<out_size, NT, 0, stream>>>(x, gm, out);
}

// Round 14
// 456.873 us; speedup vs baseline: 2.1268x; 1.1477x over previous
//
#include <hip/hip_runtime.h>
#include <hip/hip_fp16.h>
#include <math.h>

#define NQ 14
#define NL 6
#define NT 1024
#define NGATES (NL * NQ)
#define NK 8   // 8 half2 regs per re/im array = 16 amps/thread
// amp index p = (tid<<4) | j, j=0..15. Packing: bit 3 of j -> half2 halves:
// pk[k] = (amp j=k [lo], amp j=k|8 [hi]), k=0..7.
// amp bit p: p<3 local k-bit (packed gates), p==3 packing bit (cross-half),
// 4<=p<10 lane bit (tid bit p-4, shuffles), p>=10 wave bit (tid bits 6..9,
// LDS exchange). Wire w <-> amp bit P = 13-w.
// fp16 state = 16 VGPRs -> fits the 64-VGPR budget (spill-free, R13).
// R14: 64 KB exchange buffer -> whole state (pr+pi = 4 F4/thread) moves in
// ONE phase -> wave-rot 4->2 barriers, sel-CNOT 4->2. 64KB x 2 blocks/CU
// still fits 160 KB LDS.

using F4 = float4;
using H2 = __half2;

__device__ __forceinline__ unsigned h2u(H2 v){ return __builtin_bit_cast(unsigned, v); }
__device__ __forceinline__ H2 u2h(unsigned x){ return __builtin_bit_cast(H2, x); }
__device__ __forceinline__ float h2f(H2 v){ return __builtin_bit_cast(float, v); }
__device__ __forceinline__ H2 f2h(float x){ return __builtin_bit_cast(H2, x); }
__device__ __forceinline__ H2 bc(float x){ return __float2half2_rn(x); }
__device__ __forceinline__ H2 shflx(H2 v, int m){
    return u2h((unsigned)__shfl_xor((int)h2u(v), m, 64));
}

// ---- prep: Rot matrices (batch-shared, fp32) into d_ws ----
__global__ void prep_kernel(const float* __restrict__ wts, float* __restrict__ gm) {
    int g = blockIdx.x * blockDim.x + threadIdx.x;
    if (g < NGATES) {
        float phi = wts[g*3+0], th = wts[g*3+1], om = wts[g*3+2];
        float c = cosf(0.5f*th), s = sinf(0.5f*th);
        float a = 0.5f*(phi+om), bb = 0.5f*(phi-om);
        float ca = cosf(a), sa = sinf(a);
        float cb = cosf(bb), sb = sinf(bb);
        gm[g*8+0] = c*ca;  gm[g*8+1] = -c*sa;   // m00
        gm[g*8+2] = -s*cb; gm[g*8+3] = -s*sb;   // m01
        gm[g*8+4] = s*cb;  gm[g*8+5] = -s*sb;   // m10
        gm[g*8+6] = c*ca;  gm[g*8+7] = c*sa;    // m11
    }
}

// ---- Rot on amp bit P ----
template<int P>
__device__ __forceinline__ void rot_gate(H2 (&pr)[NK], H2 (&pi)[NK],
                                         const float* __restrict__ m, int tid, F4* buf) {
    float m0=m[0],m1=m[1],m2=m[2],m3=m[3],m4=m[4],m5=m[5],m6=m[6],m7=m[7];
    if constexpr (P < 3) {
        constexpr int M = 1 << P;
        H2 h0=bc(m0),h1=bc(m1),nh1=bc(-m1),h2v=bc(m2),h3=bc(m3),nh3=bc(-m3);
        H2 h4=bc(m4),h5=bc(m5),nh5=bc(-m5),h6=bc(m6),h7=bc(m7),nh7=bc(-m7);
        #pragma unroll
        for (int i = 0; i < 4; ++i) {
            int k0 = ((i >> P) << (P+1)) | (i & (M-1));
            int k1 = k0 | M;
            H2 r0=pr[k0], i0=pi[k0], r1=pr[k1], i1=pi[k1];
            pr[k0] = __hfma2(h0,r0,__hfma2(nh1,i0,__hfma2(h2v,r1,__hmul2(nh3,i1))));
            pi[k0] = __hfma2(h0,i0,__hfma2(h1,r0,__hfma2(h2v,i1,__hmul2(h3,r1))));
            pr[k1] = __hfma2(h4,r0,__hfma2(nh5,i0,__hfma2(h6,r1,__hmul2(nh7,i1))));
            pi[k1] = __hfma2(h4,i0,__hfma2(h5,r0,__hfma2(h6,i1,__hmul2(h7,r1))));
        }
    } else if constexpr (P == 3) {
        // cross-half: pairs are (lo, hi) of each reg; fp32 math
        #pragma unroll
        for (int k = 0; k < NK; ++k) {
            float r0=__low2float(pr[k]), r1=__high2float(pr[k]);
            float i0=__low2float(pi[k]), i1=__high2float(pi[k]);
            float lr = m0*r0 - m1*i0 + m2*r1 - m3*i1;
            float li = m0*i0 + m1*r0 + m2*i1 + m3*r1;
            float hr = m4*r0 - m5*i0 + m6*r1 - m7*i1;
            float hi = m4*i0 + m5*r0 + m6*i1 + m7*r1;
            pr[k] = __floats2half2_rn(lr, hr);
            pi[k] = __floats2half2_rn(li, hi);
        }
    } else if constexpr (P < 10) {
        constexpr int LM = 1 << (P-4);
        int bit = (tid >> (P-4)) & 1;
        float cAr = bit ? m6 : m0, cAi = bit ? m7 : m1;
        float cBr = bit ? m4 : m2, cBi = bit ? m5 : m3;
        H2 a=bc(cAr), ai2=bc(cAi), nai=bc(-cAi), b2=bc(cBr), bi2=bc(cBi), nbi=bc(-cBi);
        #pragma unroll
        for (int k = 0; k < NK; ++k) {
            H2 r = pr[k], i = pi[k];
            H2 qr = shflx(r, LM), qi = shflx(i, LM);
            pr[k] = __hfma2(a,r,__hfma2(nai,i,__hfma2(b2,qr,__hmul2(nbi,qi))));
            pi[k] = __hfma2(a,i,__hfma2(ai2,r,__hfma2(b2,qi,__hmul2(bi2,qr))));
        }
    } else {
        constexpr int WM = 1 << (P-4);
        int ptid = tid ^ WM;
        int bit = (tid >> (P-4)) & 1;
        float cAr = bit ? m6 : m0, cAi = bit ? m7 : m1;
        float cBr = bit ? m4 : m2, cBi = bit ? m5 : m3;
        H2 a=bc(cAr), ai2=bc(cAi), nai=bc(-cAi), b2=bc(cBr), bi2=bc(cBi), nbi=bc(-cBi);
        // single phase: whole state (pr 2 F4 + pi 2 F4) in 64 KB buffer
        buf[tid]      = make_float4(h2f(pr[0]),h2f(pr[1]),h2f(pr[2]),h2f(pr[3]));
        buf[NT+tid]   = make_float4(h2f(pr[4]),h2f(pr[5]),h2f(pr[6]),h2f(pr[7]));
        buf[2*NT+tid] = make_float4(h2f(pi[0]),h2f(pi[1]),h2f(pi[2]),h2f(pi[3]));
        buf[3*NT+tid] = make_float4(h2f(pi[4]),h2f(pi[5]),h2f(pi[6]),h2f(pi[7]));
        __syncthreads();
        F4 x = buf[ptid], y = buf[NT+ptid], z = buf[2*NT+ptid], w = buf[3*NT+ptid];
        __syncthreads();
        H2 qr[NK] = {f2h(x.x),f2h(x.y),f2h(x.z),f2h(x.w),
                     f2h(y.x),f2h(y.y),f2h(y.z),f2h(y.w)};
        H2 qi[NK] = {f2h(z.x),f2h(z.y),f2h(z.z),f2h(z.w),
                     f2h(w.x),f2h(w.y),f2h(w.z),f2h(w.w)};
        #pragma unroll
        for (int k = 0; k < NK; ++k) {
            H2 r = pr[k], i = pi[k];
            pr[k] = __hfma2(a,r,__hfma2(nai,i,__hfma2(b2,qr[k],__hmul2(nbi,qi[k]))));
            pi[k] = __hfma2(a,i,__hfma2(ai2,r,__hfma2(b2,qi[k],__hmul2(bi2,qr[k]))));
        }
    }
}

// ---- CNOT(ctrl bit PC, target bit PT) ----
template<int PC, int PT>
__device__ __forceinline__ void cnot_gate(H2 (&pr)[NK], H2 (&pi)[NK], int tid, F4* buf) {
    if constexpr (PT < 3) {
        constexpr int TM = 1 << PT;
        if constexpr (PC < 3) {
            constexpr int CM = 1 << PC;
            #pragma unroll
            for (int k = 0; k < NK; ++k)
                if ((k & CM) && !(k & TM)) {
                    int k1 = k | TM;
                    H2 t = pr[k]; pr[k] = pr[k1]; pr[k1] = t;
                    t = pi[k]; pi[k] = pi[k1]; pi[k1] = t;
                }
        } else if constexpr (PC == 3) {
            // ctrl = packing bit: swap only high halves of (k, k|TM)
            #pragma unroll
            for (int k = 0; k < NK; ++k)
                if (!(k & TM)) {
                    int k1 = k | TM;
                    unsigned A = h2u(pr[k]), B = h2u(pr[k1]);
                    pr[k]  = u2h((A & 0xFFFFu) | (B & 0xFFFF0000u));
                    pr[k1] = u2h((B & 0xFFFFu) | (A & 0xFFFF0000u));
                    A = h2u(pi[k]); B = h2u(pi[k1]);
                    pi[k]  = u2h((A & 0xFFFFu) | (B & 0xFFFF0000u));
                    pi[k1] = u2h((B & 0xFFFFu) | (A & 0xFFFF0000u));
                }
        } else if constexpr (PC < 10) {
            int sel = (tid >> (PC-4)) & 1;
            #pragma unroll
            for (int k = 0; k < NK; ++k)
                if (!(k & TM)) {
                    int k1 = k | TM;
                    H2 A = pr[k], B = pr[k1];
                    pr[k] = sel ? B : A; pr[k1] = sel ? A : B;
                    A = pi[k]; B = pi[k1];
                    pi[k] = sel ? B : A; pi[k1] = sel ? A : B;
                }
        } else {
            int sel = (tid >> (PC-4)) & 1;
            if (sel) {
                #pragma unroll
                for (int k = 0; k < NK; ++k)
                    if (!(k & TM)) {
                        int k1 = k | TM;
                        H2 t = pr[k]; pr[k] = pr[k1]; pr[k1] = t;
                        t = pi[k]; pi[k] = pi[k1]; pi[k1] = t;
                    }
            }
        }
    } else if constexpr (PT == 3) {
        // target = packing bit: swap halves where ctrl==1
        if constexpr (PC < 3) {
            constexpr int CM = 1 << PC;
            #pragma unroll
            for (int k = 0; k < NK; ++k)
                if (k & CM) {
                    unsigned A = h2u(pr[k]); pr[k] = u2h((A>>16)|(A<<16));
                    A = h2u(pi[k]); pi[k] = u2h((A>>16)|(A<<16));
                }
        } else if constexpr (PC < 10) {
            int sel = (tid >> (PC-4)) & 1;
            #pragma unroll
            for (int k = 0; k < NK; ++k) {
                unsigned A = h2u(pr[k]), S = (A>>16)|(A<<16);
                pr[k] = u2h(sel ? S : A);
                A = h2u(pi[k]); S = (A>>16)|(A<<16);
                pi[k] = u2h(sel ? S : A);
            }
        } else {
            int sel = (tid >> (PC-4)) & 1;
            if (sel) {
                #pragma unroll
                for (int k = 0; k < NK; ++k) {
                    unsigned A = h2u(pr[k]); pr[k] = u2h((A>>16)|(A<<16));
                    A = h2u(pi[k]); pi[k] = u2h((A>>16)|(A<<16));
                }
            }
        }
    } else if constexpr (PT < 10) {
        constexpr int LM = 1 << (PT-4);
        if constexpr (PC < 3) {
            constexpr int CM = 1 << PC;
            #pragma unroll
            for (int k = 0; k < NK; ++k)
                if (k & CM) { pr[k] = shflx(pr[k], LM); pi[k] = shflx(pi[k], LM); }
        } else if constexpr (PC == 3) {
            // only high halves exchange between partner lanes
            #pragma unroll
            for (int k = 0; k < NK; ++k) {
                unsigned S = h2u(shflx(pr[k], LM));
                pr[k] = u2h((h2u(pr[k]) & 0xFFFFu) | (S & 0xFFFF0000u));
                S = h2u(shflx(pi[k], LM));
                pi[k] = u2h((h2u(pi[k]) & 0xFFFFu) | (S & 0xFFFF0000u));
            }
        } else if constexpr (PC < 10) {
            int sel = (tid >> (PC-4)) & 1;   // partner (xor PT lane bit) has same sel
            #pragma unroll
            for (int k = 0; k < NK; ++k) {
                H2 sr = shflx(pr[k], LM), si = shflx(pi[k], LM);
                pr[k] = sel ? sr : pr[k];
                pi[k] = sel ? si : pi[k];
            }
        } else {
            int sel = (tid >> (PC-4)) & 1;
            if (sel) {
                #pragma unroll
                for (int k = 0; k < NK; ++k) { pr[k]=shflx(pr[k],LM); pi[k]=shflx(pi[k],LM); }
            }
        }
    } else {
        constexpr int WM = 1 << (PT-4);
        int ptid = tid ^ WM;
        if constexpr (PC < 3) {
            constexpr int CM = 1 << PC;
            // exactly 4 of 8 regs selected (both halves: ctrl is a k-bit)
            H2 vr[4], vi[4];
            { int c = 0;
              #pragma unroll
              for (int k = 0; k < NK; ++k)
                  if (k & CM) { vr[c]=pr[k]; vi[c]=pi[k]; ++c; } }
            buf[tid]    = make_float4(h2f(vr[0]),h2f(vr[1]),h2f(vr[2]),h2f(vr[3]));
            buf[NT+tid] = make_float4(h2f(vi[0]),h2f(vi[1]),h2f(vi[2]),h2f(vi[3]));
            __syncthreads();
            F4 x = buf[ptid], y = buf[NT+ptid];
            __syncthreads();
            H2 wr[4] = {f2h(x.x),f2h(x.y),f2h(x.z),f2h(x.w)};
            H2 wi[4] = {f2h(y.x),f2h(y.y),f2h(y.z),f2h(y.w)};
            { int c = 0;
              #pragma unroll
              for (int k = 0; k < NK; ++k)
                  if (k & CM) { pr[k]=wr[c]; pi[k]=wi[c]; ++c; } }
        } else if constexpr (PC == 3) {
            // only high halves exchange with partner thread
            unsigned er[4], ei[4];
            #pragma unroll
            for (int t = 0; t < 4; ++t) {
                er[t] = (h2u(pr[2*t]) >> 16) | (h2u(pr[2*t+1]) & 0xFFFF0000u);
                ei[t] = (h2u(pi[2*t]) >> 16) | (h2u(pi[2*t+1]) & 0xFFFF0000u);
            }
            buf[tid]    = make_float4(__builtin_bit_cast(float,er[0]),__builtin_bit_cast(float,er[1]),
                                      __builtin_bit_cast(float,er[2]),__builtin_bit_cast(float,er[3]));
            buf[NT+tid] = make_float4(__builtin_bit_cast(float,ei[0]),__builtin_bit_cast(float,ei[1]),
                                      __builtin_bit_cast(float,ei[2]),__builtin_bit_cast(float,ei[3]));
            __syncthreads();
            F4 x = buf[ptid], y = buf[NT+ptid];
            __syncthreads();
            unsigned fr[4] = {__builtin_bit_cast(unsigned,x.x),__builtin_bit_cast(unsigned,x.y),
                              __builtin_bit_cast(unsigned,x.z),__builtin_bit_cast(unsigned,x.w)};
            unsigned fi[4] = {__builtin_bit_cast(unsigned,y.x),__builtin_bit_cast(unsigned,y.y),
                              __builtin_bit_cast(unsigned,y.z),__builtin_bit_cast(unsigned,y.w)};
            #pragma unroll
            for (int t = 0; t < 4; ++t) {
                pr[2*t]   = u2h((h2u(pr[2*t])   & 0xFFFFu) | (fr[t] << 16));
                pr[2*t+1] = u2h((h2u(pr[2*t+1]) & 0xFFFFu) | (fr[t] & 0xFFFF0000u));
                pi[2*t]   = u2h((h2u(pi[2*t])   & 0xFFFFu) | (fi[t] << 16));
                pi[2*t+1] = u2h((h2u(pi[2*t+1]) & 0xFFFFu) | (fi[t] & 0xFFFF0000u));
            }
        } else {
            // ctrl is a thread bit != PT: sel==1 threads swap whole state,
            // single phase in the 64 KB buffer
            int sel = (tid >> (PC-4)) & 1;
            if (sel) {
                buf[tid]      = make_float4(h2f(pr[0]),h2f(pr[1]),h2f(pr[2]),h2f(pr[3]));
                buf[NT+tid]   = make_float4(h2f(pr[4]),h2f(pr[5]),h2f(pr[6]),h2f(pr[7]));
                buf[2*NT+tid] = make_float4(h2f(pi[0]),h2f(pi[1]),h2f(pi[2]),h2f(pi[3]));
                buf[3*NT+tid] = make_float4(h2f(pi[4]),h2f(pi[5]),h2f(pi[6]),h2f(pi[7]));
            }
            __syncthreads();
            if (sel) {
                F4 x = buf[ptid], y = buf[NT+ptid];
                F4 z = buf[2*NT+ptid], w = buf[3*NT+ptid];
                pr[0]=f2h(x.x); pr[1]=f2h(x.y); pr[2]=f2h(x.z); pr[3]=f2h(x.w);
                pr[4]=f2h(y.x); pr[5]=f2h(y.y); pr[6]=f2h(y.z); pr[7]=f2h(y.w);
                pi[0]=f2h(z.x); pi[1]=f2h(z.y); pi[2]=f2h(z.z); pi[3]=f2h(z.w);
                pi[4]=f2h(w.x); pi[5]=f2h(w.y); pi[6]=f2h(w.z); pi[7]=f2h(w.w);
            }
            __syncthreads();
        }
    }
}

// ---- compile-time circuit drivers ----
template<int L, int W>
__device__ __forceinline__ void do_rots(H2 (&pr)[NK], H2 (&pi)[NK],
                                        const float* __restrict__ gm, int tid, F4* buf) {
    rot_gate<13-W>(pr, pi, gm + (L*NQ + W)*8, tid, buf);
    if constexpr (W < NQ-1) do_rots<L, W+1>(pr, pi, gm, tid, buf);
}

template<int L, int W>
__device__ __forceinline__ void do_cnots(H2 (&pr)[NK], H2 (&pi)[NK], int tid, F4* buf) {
    constexpr int R = (L % (NQ-1)) + 1;
    constexpr int TW = (W + R) % NQ;
    cnot_gate<13-W, 13-TW>(pr, pi, tid, buf);
    if constexpr (W < NQ-1) do_cnots<L, W+1>(pr, pi, tid, buf);
}

template<int L>
__device__ __forceinline__ void do_layer(H2 (&pr)[NK], H2 (&pi)[NK],
                                         const float* __restrict__ gm, int tid, F4* buf) {
    do_rots<L, 0>(pr, pi, gm, tid, buf);
    do_cnots<L, 0>(pr, pi, tid, buf);
    if constexpr (L < NL-1) do_layer<L+1>(pr, pi, gm, tid, buf);
}

__global__ void __launch_bounds__(NT)
qsim_kernel(
    const float* __restrict__ x,
    const float* __restrict__ gm,
    float* __restrict__ out)
{
    __shared__ F4 buf[4 * NT];   // static 64 KB -> whole state in one phase; 2 blocks/CU
    const int tid = threadIdx.x;
    const int b = blockIdx.x;
    const float* xb = x + b * NQ;

    // ---- direct product-state init (fp32 math, pack to fp16) ----
    // amp(p) = prod_bits [ bit ? -i*sin(x/2) : cos(x/2) ]
    H2 pr[NK], pi[NK];
    {
        float cr = 1.f, ci = 0.f;
        #pragma unroll
        for (int bb = 0; bb < 10; ++bb) {      // tid bit bb = amp bit 4+bb = wire 9-bb
            float t = xb[9 - bb];
            float c = cosf(0.5f*t), s = sinf(0.5f*t);
            if ((tid >> bb) & 1) { float nr = s*ci, ni = -s*cr; cr = nr; ci = ni; }
            else                 { cr *= c; ci *= c; }
        }
        float lc[4], ls[4];                     // j bit bb = wire 13-bb
        #pragma unroll
        for (int bb = 0; bb < 4; ++bb) {
            float t = xb[13 - bb];
            lc[bb] = cosf(0.5f*t); ls[bb] = sinf(0.5f*t);
        }
        #pragma unroll
        for (int k = 0; k < NK; ++k) {
            float rr = cr, ii = ci;
            #pragma unroll
            for (int bb = 0; bb < 3; ++bb) {
                if ((k >> bb) & 1) { float nr = ls[bb]*ii, ni = -ls[bb]*rr; rr = nr; ii = ni; }
                else               { rr *= lc[bb]; ii *= lc[bb]; }
            }
            // packing bit 3: lo = *cos, hi = -i*sin rotation
            pr[k] = __floats2half2_rn(rr*lc[3],  ls[3]*ii);
            pi[k] = __floats2half2_rn(ii*lc[3], -ls[3]*rr);
        }
    }
    __syncthreads();

    do_layer<0>(pr, pi, gm, tid, buf);

    // <Z0>: amp bit 13 = tid bit 9 -> sign uniform per thread
    float acc = 0.f;
    #pragma unroll
    for (int k = 0; k < NK; ++k) {
        float a=__low2float(pr[k]), bb=__high2float(pr[k]);
        float c=__low2float(pi[k]), d=__high2float(pi[k]);
        acc += a*a + bb*bb + c*c + d*d;
    }
    if (tid & 512) acc = -acc;
    #pragma unroll
    for (int off = 32; off > 0; off >>= 1) acc += __shfl_down(acc, off, 64);
    __syncthreads();
    float* f = (float*)buf;
    if ((tid & 63) == 0) f[tid >> 6] = acc;
    __syncthreads();
    if (tid == 0) {
        float s = 0.f;
        #pragma unroll
        for (int w = 0; w < NT/64; ++w) s += f[w];
        out[b] = s;
    }
}

extern "C" void kernel_launch(void* const* d_in, const int* in_sizes, int n_in,
                              void* d_out, int out_size, void* d_ws, size_t ws_size,
                              hipStream_t stream) {
    const float* x = (const float*)d_in[0];   // (1024, 14) float32
    const float* w = (const float*)d_in[1];   // (6, 14, 3) float32
    float* out = (float*)d_out;               // (1024,) float32
    float* gm = (float*)d_ws;                 // 84*8 floats of Rot matrices

    prep_kernel<<<1, 128, 0, stream>>>(w, gm);
    qsim_kernel<<<out_size, NT, 0, stream>>>(x, gm, out);
}